// Round 1
// baseline (2658.342 us; speedup 1.0000x reference)
//
#include <hip/hip_runtime.h>
#include <hip/hip_bf16.h>

constexpr int BATCH = 4, SEQLEN = 2048, DM = 1024, DI = 2048, DS = 16, DC = 4, DTR = 64;
constexpr int M = BATCH * SEQLEN;      // 8192
constexpr int NXZ = 2 * DI;            // 4096
constexpr int NXDBL = DTR + 2 * DS;    // 96

typedef __attribute__((ext_vector_type(8))) short short8;
typedef __attribute__((ext_vector_type(4))) float f32x4;

// ---------- f32 -> bf16 convert (4 elems/thread) ----------
__global__ __launch_bounds__(256) void k_cvt(const float* __restrict__ s,
                                             __hip_bfloat16* __restrict__ d, int n) {
  int i = (blockIdx.x * 256 + threadIdx.x) * 4;
  if (i + 3 < n) {
    float4 v = *reinterpret_cast<const float4*>(s + i);
    d[i + 0] = __float2bfloat16(v.x);
    d[i + 1] = __float2bfloat16(v.y);
    d[i + 2] = __float2bfloat16(v.z);
    d[i + 3] = __float2bfloat16(v.w);
  }
}

// ---------- A = -exp(A_log) ----------
__global__ __launch_bounds__(256) void k_prepA(const float* __restrict__ alog,
                                               float* __restrict__ an, int n) {
  int i = blockIdx.x * 256 + threadIdx.x;
  if (i < n) an[i] = -__expf(alog[i]);
}

// ---------- bf16 NT GEMM: C[M,N] = A[M,K] * B[N,K]^T ----------
// 4 waves (2x2), each wave computes (BM/2)x(BN/2) via 16x16x32 bf16 MFMA.
template <int BM, int BN, bool OUT_BF16>
__global__ __launch_bounds__(256) void k_gemm_bt(const __hip_bfloat16* __restrict__ A, int lda,
                                                 const __hip_bfloat16* __restrict__ Bm, int ldb,
                                                 void* __restrict__ Cp, int ldc, int K) {
  constexpr int BK = 32;
  constexpr int WM = BM / 2;
  constexpr int WN = BN / 2;
  constexpr int FM = WM / 16;
  constexpr int FN = WN / 16;

  const int tid = threadIdx.x;
  const int wid = tid >> 6;
  const int lane = tid & 63;
  const int wm = wid >> 1, wn = wid & 1;
  const int bm0 = blockIdx.y * BM;
  const int bn0 = blockIdx.x * BN;

  __shared__ short As[BM][40];  // +8 pad: bank-conflict-free ds_read_b128
  __shared__ short Bs[BN][40];

  f32x4 acc[FM][FN] = {};

  const int trow = tid >> 2;        // 0..63
  const int tcol = (tid & 3) * 8;   // 0,8,16,24
  const int lrow = lane & 15;
  const int lk = (lane >> 4) * 8;

  for (int k0 = 0; k0 < K; k0 += BK) {
    __syncthreads();
#pragma unroll
    for (int h = 0; h < BM; h += 64) {
      int r = h + trow;
      uint4 v = *reinterpret_cast<const uint4*>(&A[(size_t)(bm0 + r) * lda + k0 + tcol]);
      *reinterpret_cast<uint4*>(&As[r][tcol]) = v;
    }
#pragma unroll
    for (int h = 0; h < BN; h += 64) {
      int r = h + trow;
      if ((BN % 64 == 0) || (r < BN)) {
        uint4 v = *reinterpret_cast<const uint4*>(&Bm[(size_t)(bn0 + r) * ldb + k0 + tcol]);
        *reinterpret_cast<uint4*>(&Bs[r][tcol]) = v;
      }
    }
    __syncthreads();

    short8 af[FM], bf[FN];
#pragma unroll
    for (int i = 0; i < FM; i++)
      af[i] = *reinterpret_cast<const short8*>(&As[wm * WM + i * 16 + lrow][lk]);
#pragma unroll
    for (int j = 0; j < FN; j++)
      bf[j] = *reinterpret_cast<const short8*>(&Bs[wn * WN + j * 16 + lrow][lk]);
#pragma unroll
    for (int i = 0; i < FM; i++)
#pragma unroll
      for (int j = 0; j < FN; j++)
        acc[i][j] = __builtin_amdgcn_mfma_f32_16x16x32_bf16(af[i], bf[j], acc[i][j], 0, 0, 0);
  }

  const int crow0 = bm0 + wm * WM + (lane >> 4) * 4;
  const int ccol0 = bn0 + wn * WN + lrow;
#pragma unroll
  for (int i = 0; i < FM; i++)
#pragma unroll
    for (int j = 0; j < FN; j++)
#pragma unroll
      for (int r = 0; r < 4; r++) {
        int row = crow0 + i * 16 + r;
        int col = ccol0 + j * 16;
        float v = acc[i][j][r];
        if constexpr (OUT_BF16)
          reinterpret_cast<__hip_bfloat16*>(Cp)[(size_t)row * ldc + col] = __float2bfloat16(v);
        else
          reinterpret_cast<float*>(Cp)[(size_t)row * ldc + col] = v;
      }
}

// ---------- causal depthwise conv (width 4) + bias + silu ----------
__global__ __launch_bounds__(256) void k_conv(const __hip_bfloat16* __restrict__ xz,
                                              const float* __restrict__ cw,
                                              const float* __restrict__ cb,
                                              __hip_bfloat16* __restrict__ xc_bf16) {
  int idx = blockIdx.x * 256 + threadIdx.x;  // over M*DI
  int d = idx & (DI - 1);
  int ml = idx >> 11;
  int l = ml & (SEQLEN - 1);
  float acc = cb[d];
#pragma unroll
  for (int w = 0; w < DC; w++) {
    int li = l - 3 + w;
    if (li >= 0) {
      float xv = __bfloat162float(xz[(size_t)(ml - 3 + w) * NXZ + d]);
      acc += xv * cw[d * DC + w];
    }
  }
  float s = acc / (1.f + __expf(-acc));
  xc_bf16[idx] = __float2bfloat16(s);
}

// ---------- x_dbl[:, :64] -> bf16 dt_in ----------
__global__ __launch_bounds__(256) void k_dtin(const float* __restrict__ xdbl,
                                              __hip_bfloat16* __restrict__ dtin) {
  int i = blockIdx.x * 256 + threadIdx.x;  // M*64
  int r = i >> 6, c = i & 63;
  dtin[i] = __float2bfloat16(xdbl[(size_t)r * NXDBL + c]);
}

// ---------- sequential selective scan, fused softplus + D-skip + z-gate ----------
__global__ __launch_bounds__(256) void k_scan(const float* __restrict__ dtraw,
                                              const float* __restrict__ dtb,
                                              const float* __restrict__ xdbl,
                                              const __hip_bfloat16* __restrict__ xc,
                                              const __hip_bfloat16* __restrict__ xz,
                                              const float* __restrict__ Aneg,
                                              const float* __restrict__ Dw,
                                              __hip_bfloat16* __restrict__ yg) {
  const int tid = threadIdx.x;
  const int b = blockIdx.x >> 3;
  const int d = (blockIdx.x & 7) * 256 + tid;

  float h[DS] = {};
  float Ar[DS];
#pragma unroll
  for (int n = 0; n < DS; n++) Ar[n] = Aneg[d * DS + n];
  const float dtbv = dtb[d], Dv = Dw[d];

  __shared__ float bc[32][32];  // [l_in_chunk][n: 0..15 = B, 16..31 = C]
  const size_t rowbase = (size_t)b * SEQLEN;

  for (int l0 = 0; l0 < SEQLEN; l0 += 32) {
    __syncthreads();
    {
      int i0 = tid * 4;
      int li = i0 >> 5, n0 = i0 & 31;
      const float* src = &xdbl[(rowbase + l0 + li) * NXDBL + DTR + n0];
      float4 v = *reinterpret_cast<const float4*>(src);
      *reinterpret_cast<float4*>(&bc[li][n0]) = v;
    }
    __syncthreads();

    for (int ls = 0; ls < 32; ls++) {
      const size_t mrow = rowbase + l0 + ls;
      const size_t idx = mrow * DI + d;
      float dpre = dtraw[idx] + dtbv;
      float delta = (dpre > 20.f) ? dpre : __logf(1.f + __expf(dpre));
      float u = __bfloat162float(xc[idx]);
      float du = delta * u;
      float y = 0.f;
#pragma unroll
      for (int n = 0; n < DS; n++) {
        float dA = __expf(delta * Ar[n]);
        h[n] = h[n] * dA + du * bc[ls][n];
        y += h[n] * bc[ls][16 + n];
      }
      float zv = __bfloat162float(xz[mrow * NXZ + DI + d]);
      float sz = zv / (1.f + __expf(-zv));
      float out = (y + u * Dv) * sz;
      yg[idx] = __float2bfloat16(out);
    }
  }
}

extern "C" void kernel_launch(void* const* d_in, const int* in_sizes, int n_in,
                              void* d_out, int out_size, void* d_ws, size_t ws_size,
                              hipStream_t stream) {
  const float* hs = (const float*)d_in[0];
  const float* w_in = (const float*)d_in[1];
  const float* conv_w = (const float*)d_in[2];
  const float* conv_b = (const float*)d_in[3];
  const float* w_xp = (const float*)d_in[4];
  const float* w_dt = (const float*)d_in[5];
  const float* dt_b = (const float*)d_in[6];
  const float* A_log = (const float*)d_in[7];
  const float* Dw = (const float*)d_in[8];
  const float* w_out = (const float*)d_in[9];
  float* out = (float*)d_out;

  char* ws = (char*)d_ws;
  size_t off = 0;
  auto alloc = [&](size_t bytes) {
    void* p = ws + off;
    off += (bytes + 255) & ~(size_t)255;
    return p;
  };

  __hip_bfloat16* hs_b   = (__hip_bfloat16*)alloc((size_t)M * DM * 2);
  __hip_bfloat16* win_b  = (__hip_bfloat16*)alloc((size_t)NXZ * DM * 2);
  __hip_bfloat16* wxp_b  = (__hip_bfloat16*)alloc((size_t)NXDBL * DI * 2);
  __hip_bfloat16* wdt_b  = (__hip_bfloat16*)alloc((size_t)DI * DTR * 2);
  __hip_bfloat16* wout_b = (__hip_bfloat16*)alloc((size_t)DM * DI * 2);
  float*          Aneg   = (float*)alloc((size_t)DI * DS * 4);
  __hip_bfloat16* xz_b   = (__hip_bfloat16*)alloc((size_t)M * NXZ * 2);
  __hip_bfloat16* xc_b   = (__hip_bfloat16*)alloc((size_t)M * DI * 2);
  float*          xdbl   = (float*)alloc((size_t)M * NXDBL * 4);
  __hip_bfloat16* dtin_b = (__hip_bfloat16*)alloc((size_t)M * DTR * 2);
  float*          dtraw  = (float*)alloc((size_t)M * DI * 4);
  __hip_bfloat16* yg_b   = (__hip_bfloat16*)alloc((size_t)M * DI * 2);

  // 1) conversions
  k_cvt<<<(M * DM) / 1024, 256, 0, stream>>>(hs, hs_b, M * DM);
  k_cvt<<<(NXZ * DM) / 1024, 256, 0, stream>>>(w_in, win_b, NXZ * DM);
  k_cvt<<<(NXDBL * DI) / 1024, 256, 0, stream>>>(w_xp, wxp_b, NXDBL * DI);
  k_cvt<<<(DI * DTR) / 1024, 256, 0, stream>>>(w_dt, wdt_b, DI * DTR);
  k_cvt<<<(DM * DI) / 1024, 256, 0, stream>>>(w_out, wout_b, DM * DI);
  k_prepA<<<(DI * DS) / 256, 256, 0, stream>>>(A_log, Aneg, DI * DS);

  // 2) xz = hs @ in_proj_w^T  (M x 4096)
  k_gemm_bt<128, 128, true><<<dim3(NXZ / 128, M / 128), 256, 0, stream>>>(
      hs_b, DM, win_b, DM, xz_b, NXZ, DM);

  // 3) conv + silu -> x_conv (bf16)
  k_conv<<<(M * DI) / 256, 256, 0, stream>>>(xz_b, conv_w, conv_b, xc_b);

  // 4) x_dbl = x_conv @ x_proj_w^T  (M x 96, fp32)
  k_gemm_bt<128, 96, false><<<dim3(1, M / 128), 256, 0, stream>>>(
      xc_b, DI, wxp_b, DI, xdbl, NXDBL, DI);

  // 5) dt_in -> bf16
  k_dtin<<<(M * DTR) / 256, 256, 0, stream>>>(xdbl, dtin_b);

  // 6) dt_raw = dt_in @ dt_proj_w^T  (M x 2048, fp32)
  k_gemm_bt<128, 128, false><<<dim3(DI / 128, M / 128), 256, 0, stream>>>(
      dtin_b, DTR, wdt_b, DTR, dtraw, DI, DTR);

  // 7) selective scan + gate -> y_gated (bf16)
  k_scan<<<BATCH * (DI / 256), 256, 0, stream>>>(dtraw, dt_b, xdbl, xc_b, xz_b,
                                                 Aneg, Dw, yg_b);

  // 8) out = y_gated @ out_proj_w^T  (M x 1024, fp32)
  k_gemm_bt<128, 128, false><<<dim3(DM / 128, M / 128), 256, 0, stream>>>(
      yg_b, DI, wout_b, DI, out, DM, DI);
}

// Round 2
// 495.960 us; speedup vs baseline: 5.3600x; 5.3600x over previous
//
#include <hip/hip_runtime.h>
#include <hip/hip_bf16.h>

constexpr int BATCH = 4, SEQLEN = 2048, DM = 1024, DI = 2048, DS = 16, DC = 4, DTR = 64;
constexpr int M = BATCH * SEQLEN;      // 8192
constexpr int NXZ = 2 * DI;            // 4096
constexpr int NXDBL = DTR + 2 * DS;    // 96
constexpr int CL = 128;                // scan chunk length
constexpr int NCH = SEQLEN / CL;       // 16 chunks
constexpr size_t CS = (size_t)BATCH * DI * DS;  // per-chunk state stride (131072)

typedef __attribute__((ext_vector_type(8))) short short8;
typedef __attribute__((ext_vector_type(4))) float f32x4;

// ---------- f32 -> bf16 convert (4 elems/thread) ----------
__global__ __launch_bounds__(256) void k_cvt(const float* __restrict__ s,
                                             __hip_bfloat16* __restrict__ d, int n) {
  int i = (blockIdx.x * 256 + threadIdx.x) * 4;
  if (i + 3 < n) {
    float4 v = *reinterpret_cast<const float4*>(s + i);
    d[i + 0] = __float2bfloat16(v.x);
    d[i + 1] = __float2bfloat16(v.y);
    d[i + 2] = __float2bfloat16(v.z);
    d[i + 3] = __float2bfloat16(v.w);
  }
}

// ---------- A = -exp(A_log) ----------
__global__ __launch_bounds__(256) void k_prepA(const float* __restrict__ alog,
                                               float* __restrict__ an, int n) {
  int i = blockIdx.x * 256 + threadIdx.x;
  if (i < n) an[i] = -__expf(alog[i]);
}

// ---------- bf16 NT GEMM: C[M,N] = A[M,K] * B[N,K]^T ----------
template <int BM, int BN, bool OUT_BF16>
__global__ __launch_bounds__(256) void k_gemm_bt(const __hip_bfloat16* __restrict__ A, int lda,
                                                 const __hip_bfloat16* __restrict__ Bm, int ldb,
                                                 void* __restrict__ Cp, int ldc, int K) {
  constexpr int BK = 32;
  constexpr int WM = BM / 2;
  constexpr int WN = BN / 2;
  constexpr int FM = WM / 16;
  constexpr int FN = WN / 16;

  const int tid = threadIdx.x;
  const int wid = tid >> 6;
  const int lane = tid & 63;
  const int wm = wid >> 1, wn = wid & 1;
  const int bm0 = blockIdx.y * BM;
  const int bn0 = blockIdx.x * BN;

  __shared__ short As[BM][40];  // +8 pad: bank-conflict-free ds_read_b128
  __shared__ short Bs[BN][40];

  f32x4 acc[FM][FN] = {};

  const int trow = tid >> 2;        // 0..63
  const int tcol = (tid & 3) * 8;   // 0,8,16,24
  const int lrow = lane & 15;
  const int lk = (lane >> 4) * 8;

  for (int k0 = 0; k0 < K; k0 += BK) {
    __syncthreads();
#pragma unroll
    for (int h = 0; h < BM; h += 64) {
      int r = h + trow;
      uint4 v = *reinterpret_cast<const uint4*>(&A[(size_t)(bm0 + r) * lda + k0 + tcol]);
      *reinterpret_cast<uint4*>(&As[r][tcol]) = v;
    }
#pragma unroll
    for (int h = 0; h < BN; h += 64) {
      int r = h + trow;
      if ((BN % 64 == 0) || (r < BN)) {
        uint4 v = *reinterpret_cast<const uint4*>(&Bm[(size_t)(bn0 + r) * ldb + k0 + tcol]);
        *reinterpret_cast<uint4*>(&Bs[r][tcol]) = v;
      }
    }
    __syncthreads();

    short8 af[FM], bf[FN];
#pragma unroll
    for (int i = 0; i < FM; i++)
      af[i] = *reinterpret_cast<const short8*>(&As[wm * WM + i * 16 + lrow][lk]);
#pragma unroll
    for (int j = 0; j < FN; j++)
      bf[j] = *reinterpret_cast<const short8*>(&Bs[wn * WN + j * 16 + lrow][lk]);
#pragma unroll
    for (int i = 0; i < FM; i++)
#pragma unroll
      for (int j = 0; j < FN; j++)
        acc[i][j] = __builtin_amdgcn_mfma_f32_16x16x32_bf16(af[i], bf[j], acc[i][j], 0, 0, 0);
  }

  const int crow0 = bm0 + wm * WM + (lane >> 4) * 4;
  const int ccol0 = bn0 + wn * WN + lrow;
#pragma unroll
  for (int i = 0; i < FM; i++)
#pragma unroll
    for (int j = 0; j < FN; j++)
#pragma unroll
      for (int r = 0; r < 4; r++) {
        int row = crow0 + i * 16 + r;
        int col = ccol0 + j * 16;
        float v = acc[i][j][r];
        if constexpr (OUT_BF16)
          reinterpret_cast<__hip_bfloat16*>(Cp)[(size_t)row * ldc + col] = __float2bfloat16(v);
        else
          reinterpret_cast<float*>(Cp)[(size_t)row * ldc + col] = v;
      }
}

// ---------- causal depthwise conv (width 4) + bias + silu ----------
__global__ __launch_bounds__(256) void k_conv(const __hip_bfloat16* __restrict__ xz,
                                              const float* __restrict__ cw,
                                              const float* __restrict__ cb,
                                              __hip_bfloat16* __restrict__ xc_bf16) {
  int idx = blockIdx.x * 256 + threadIdx.x;  // over M*DI
  int d = idx & (DI - 1);
  int ml = idx >> 11;
  int l = ml & (SEQLEN - 1);
  float acc = cb[d];
#pragma unroll
  for (int w = 0; w < DC; w++) {
    int li = l - 3 + w;
    if (li >= 0) {
      float xv = __bfloat162float(xz[(size_t)(ml - 3 + w) * NXZ + d]);
      acc += xv * cw[d * DC + w];
    }
  }
  float s = acc / (1.f + __expf(-acc));
  xc_bf16[idx] = __float2bfloat16(s);
}

// ---------- x_dbl[:, :64] -> bf16 dt_in ----------
__global__ __launch_bounds__(256) void k_dtin(const float* __restrict__ xdbl,
                                              __hip_bfloat16* __restrict__ dtin) {
  int i = blockIdx.x * 256 + threadIdx.x;  // M*64
  int r = i >> 6, c = i & 63;
  dtin[i] = __float2bfloat16(xdbl[(size_t)r * NXDBL + c]);
}

__device__ __forceinline__ float softplusf(float x) {
  return (x > 20.f) ? x : __logf(1.f + __expf(x));
}

// ---------- scan pass 1: per-chunk local scan from h=0 -> (P, S) ----------
__global__ __launch_bounds__(256) void k_scan1(const float* __restrict__ dtraw,
                                               const float* __restrict__ dtb,
                                               const float* __restrict__ xdbl,
                                               const __hip_bfloat16* __restrict__ xc,
                                               const float* __restrict__ Aneg,
                                               float* __restrict__ Pb,
                                               float* __restrict__ Sb) {
  const int tid = threadIdx.x;
  const int d = blockIdx.x * 256 + tid;
  const int c = blockIdx.y, b = blockIdx.z;
  const size_t row0 = (size_t)b * SEQLEN + (size_t)c * CL;

  __shared__ float Bs[CL][16];
  {
    int i = tid * 8;                 // 128*16 = 2048 floats, 8 per thread
    int li = i >> 4, n0 = i & 15;    // n0 in {0,8}
    const float* src = &xdbl[(row0 + li) * NXDBL + DTR + n0];
    *reinterpret_cast<float4*>(&Bs[li][n0]) = *reinterpret_cast<const float4*>(src);
    *reinterpret_cast<float4*>(&Bs[li][n0 + 4]) = *reinterpret_cast<const float4*>(src + 4);
  }

  float Ar[DS];
#pragma unroll
  for (int n = 0; n < DS; n++) Ar[n] = Aneg[d * DS + n];
  const float dtbv = dtb[d];
  __syncthreads();

  float h[DS] = {};
  float sdelta = 0.f;
  size_t idx = row0 * DI + d;
  float nx_dt = dtraw[idx];
  float nx_u = __bfloat162float(xc[idx]);
  for (int ls = 0; ls < CL; ls++) {
    float dpre = nx_dt + dtbv;
    float u = nx_u;
    if (ls + 1 < CL) {
      size_t idx2 = idx + DI;
      nx_dt = dtraw[idx2];
      nx_u = __bfloat162float(xc[idx2]);
    }
    idx += DI;
    float delta = softplusf(dpre);
    sdelta += delta;
    float du = delta * u;
#pragma unroll
    for (int n = 0; n < DS; n++) {
      float dA = __expf(delta * Ar[n]);
      h[n] = fmaf(h[n], dA, du * Bs[ls][n]);
    }
  }

  size_t base = (size_t)c * CS + ((size_t)b * DI + d) * DS;
#pragma unroll
  for (int n = 0; n < DS; n += 4) {
    float4 hv = {h[n], h[n + 1], h[n + 2], h[n + 3]};
    *reinterpret_cast<float4*>(&Sb[base + n]) = hv;
    float4 pv = {__expf(Ar[n] * sdelta), __expf(Ar[n + 1] * sdelta),
                 __expf(Ar[n + 2] * sdelta), __expf(Ar[n + 3] * sdelta)};
    *reinterpret_cast<float4*>(&Pb[base + n]) = pv;
  }
}

// ---------- scan pass 2: sequential scan over chunk transfer functions ----------
__global__ __launch_bounds__(256) void k_scan2(const float* __restrict__ Pb,
                                               const float* __restrict__ Sb,
                                               float* __restrict__ Hin) {
  size_t t = (size_t)blockIdx.x * 256 + threadIdx.x;  // < CS
  float h = 0.f;
  for (int c = 0; c < NCH; c++) {
    size_t o = (size_t)c * CS + t;
    Hin[o] = h;
    h = fmaf(Pb[o], h, Sb[o]);
  }
}

// ---------- scan pass 3: re-scan with correct h_init, compute y + gate ----------
__global__ __launch_bounds__(256) void k_scan3(const float* __restrict__ dtraw,
                                               const float* __restrict__ dtb,
                                               const float* __restrict__ xdbl,
                                               const __hip_bfloat16* __restrict__ xc,
                                               const __hip_bfloat16* __restrict__ xz,
                                               const float* __restrict__ Aneg,
                                               const float* __restrict__ Dw,
                                               const float* __restrict__ Hin,
                                               __hip_bfloat16* __restrict__ yg) {
  const int tid = threadIdx.x;
  const int d = blockIdx.x * 256 + tid;
  const int c = blockIdx.y, b = blockIdx.z;
  const size_t row0 = (size_t)b * SEQLEN + (size_t)c * CL;

  __shared__ float BCs[CL][32];  // [l][0..15]=B, [16..31]=C
  {
    int i = tid * 16;              // 128*32 = 4096 floats, 16 per thread
    int li = i >> 5, n0 = i & 31;  // n0 in {0,16}
    const float* src = &xdbl[(row0 + li) * NXDBL + DTR + n0];
#pragma unroll
    for (int q = 0; q < 4; q++)
      *reinterpret_cast<float4*>(&BCs[li][n0 + q * 4]) =
          *reinterpret_cast<const float4*>(src + q * 4);
  }

  float Ar[DS];
#pragma unroll
  for (int n = 0; n < DS; n++) Ar[n] = Aneg[d * DS + n];
  const float dtbv = dtb[d];
  const float Dv = Dw[d];

  float h[DS];
  {
    size_t hbase = (size_t)c * CS + ((size_t)b * DI + d) * DS;
#pragma unroll
    for (int n = 0; n < DS; n += 4) {
      float4 hv = *reinterpret_cast<const float4*>(&Hin[hbase + n]);
      h[n] = hv.x; h[n + 1] = hv.y; h[n + 2] = hv.z; h[n + 3] = hv.w;
    }
  }
  __syncthreads();

  size_t idx = row0 * DI + d;
  float nx_dt = dtraw[idx];
  float nx_u = __bfloat162float(xc[idx]);
  float nx_z = __bfloat162float(xz[row0 * NXZ + DI + d]);
  for (int ls = 0; ls < CL; ls++) {
    const size_t cur = idx;
    float dpre = nx_dt + dtbv;
    float u = nx_u;
    float zv = nx_z;
    if (ls + 1 < CL) {
      size_t idx2 = idx + DI;
      nx_dt = dtraw[idx2];
      nx_u = __bfloat162float(xc[idx2]);
      nx_z = __bfloat162float(xz[(row0 + ls + 1) * NXZ + DI + d]);
    }
    idx += DI;
    float delta = softplusf(dpre);
    float du = delta * u;
    float y = 0.f;
#pragma unroll
    for (int n = 0; n < DS; n++) {
      float dA = __expf(delta * Ar[n]);
      h[n] = fmaf(h[n], dA, du * BCs[ls][n]);
      y = fmaf(h[n], BCs[ls][16 + n], y);
    }
    float sz = zv / (1.f + __expf(-zv));
    float out = (y + u * Dv) * sz;
    yg[cur] = __float2bfloat16(out);
  }
}

extern "C" void kernel_launch(void* const* d_in, const int* in_sizes, int n_in,
                              void* d_out, int out_size, void* d_ws, size_t ws_size,
                              hipStream_t stream) {
  const float* hs = (const float*)d_in[0];
  const float* w_in = (const float*)d_in[1];
  const float* conv_w = (const float*)d_in[2];
  const float* conv_b = (const float*)d_in[3];
  const float* w_xp = (const float*)d_in[4];
  const float* w_dt = (const float*)d_in[5];
  const float* dt_b = (const float*)d_in[6];
  const float* A_log = (const float*)d_in[7];
  const float* Dw = (const float*)d_in[8];
  const float* w_out = (const float*)d_in[9];
  float* out = (float*)d_out;

  char* ws = (char*)d_ws;
  size_t off = 0;
  auto alloc = [&](size_t bytes) {
    void* p = ws + off;
    off += (bytes + 255) & ~(size_t)255;
    return p;
  };

  __hip_bfloat16* hs_b   = (__hip_bfloat16*)alloc((size_t)M * DM * 2);     // [0, 16Mi)
  __hip_bfloat16* win_b  = (__hip_bfloat16*)alloc((size_t)NXZ * DM * 2);   // [16Mi, 24Mi)
  __hip_bfloat16* wxp_b  = (__hip_bfloat16*)alloc((size_t)NXDBL * DI * 2);
  __hip_bfloat16* wdt_b  = (__hip_bfloat16*)alloc((size_t)DI * DTR * 2);
  __hip_bfloat16* wout_b = (__hip_bfloat16*)alloc((size_t)DM * DI * 2);
  float*          Aneg   = (float*)alloc((size_t)DI * DS * 4);
  __hip_bfloat16* xz_b   = (__hip_bfloat16*)alloc((size_t)M * NXZ * 2);
  __hip_bfloat16* xc_b   = (__hip_bfloat16*)alloc((size_t)M * DI * 2);
  float*          xdbl   = (float*)alloc((size_t)M * NXDBL * 4);
  __hip_bfloat16* dtin_b = (__hip_bfloat16*)alloc((size_t)M * DTR * 2);
  float*          dtraw  = (float*)alloc((size_t)M * DI * 4);
  __hip_bfloat16* yg_b   = (__hip_bfloat16*)alloc((size_t)M * DI * 2);

  // Scan chunk-state buffers alias hs_b/win_b (dead after GEMM1; each pass
  // fully rewrites them, so graph replay is deterministic).
  // P: [0, 8Mi), S: [8Mi, 16Mi), Hin: [16Mi, 24Mi). Each is NCH*CS*4 = 8Mi.
  float* Pb  = (float*)(ws + 0);
  float* Sb  = (float*)(ws + ((size_t)8 << 20));
  float* Hin = (float*)(ws + ((size_t)16 << 20));

  // 1) conversions
  k_cvt<<<(M * DM) / 1024, 256, 0, stream>>>(hs, hs_b, M * DM);
  k_cvt<<<(NXZ * DM) / 1024, 256, 0, stream>>>(w_in, win_b, NXZ * DM);
  k_cvt<<<(NXDBL * DI) / 1024, 256, 0, stream>>>(w_xp, wxp_b, NXDBL * DI);
  k_cvt<<<(DI * DTR) / 1024, 256, 0, stream>>>(w_dt, wdt_b, DI * DTR);
  k_cvt<<<(DM * DI) / 1024, 256, 0, stream>>>(w_out, wout_b, DM * DI);
  k_prepA<<<(DI * DS) / 256, 256, 0, stream>>>(A_log, Aneg, DI * DS);

  // 2) xz = hs @ in_proj_w^T  (M x 4096)
  k_gemm_bt<128, 128, true><<<dim3(NXZ / 128, M / 128), 256, 0, stream>>>(
      hs_b, DM, win_b, DM, xz_b, NXZ, DM);

  // 3) conv + silu -> x_conv (bf16)
  k_conv<<<(M * DI) / 256, 256, 0, stream>>>(xz_b, conv_w, conv_b, xc_b);

  // 4) x_dbl = x_conv @ x_proj_w^T  (M x 96, fp32)
  k_gemm_bt<128, 96, false><<<dim3(1, M / 128), 256, 0, stream>>>(
      xc_b, DI, wxp_b, DI, xdbl, NXDBL, DI);

  // 5) dt_in -> bf16
  k_dtin<<<(M * DTR) / 256, 256, 0, stream>>>(xdbl, dtin_b);

  // 6) dt_raw = dt_in @ dt_proj_w^T  (M x 2048, fp32)
  k_gemm_bt<128, 128, false><<<dim3(DI / 128, M / 128), 256, 0, stream>>>(
      dtin_b, DTR, wdt_b, DTR, dtraw, DI, DTR);

  // 7) chunked parallel scan
  k_scan1<<<dim3(DI / 256, NCH, BATCH), 256, 0, stream>>>(dtraw, dt_b, xdbl, xc_b,
                                                          Aneg, Pb, Sb);
  k_scan2<<<(int)(CS / 256), 256, 0, stream>>>(Pb, Sb, Hin);
  k_scan3<<<dim3(DI / 256, NCH, BATCH), 256, 0, stream>>>(dtraw, dt_b, xdbl, xc_b,
                                                          xz_b, Aneg, Dw, Hin, yg_b);

  // 8) out = y_gated @ out_proj_w^T  (M x 1024, fp32)
  k_gemm_bt<128, 128, false><<<dim3(DM / 128, M / 128), 256, 0, stream>>>(
      yg_b, DI, wout_b, DI, out, DM, DI);
}

// Round 3
// 430.250 us; speedup vs baseline: 6.1786x; 1.1527x over previous
//
#include <hip/hip_runtime.h>
#include <hip/hip_bf16.h>

constexpr int BATCH = 4, SEQLEN = 2048, DM = 1024, DI = 2048, DS = 16, DC = 4, DTR = 64;
constexpr int M = BATCH * SEQLEN;      // 8192
constexpr int NXZ = 2 * DI;            // 4096
constexpr int NXDBL = DTR + 2 * DS;    // 96
constexpr int CL = 128;                // scan chunk length
constexpr int NCH = SEQLEN / CL;       // 16 chunks
constexpr size_t CS = (size_t)BATCH * DI * DS;  // per-chunk state stride (131072)

typedef __attribute__((ext_vector_type(8))) short short8;
typedef __attribute__((ext_vector_type(4))) float f32x4;

__device__ __forceinline__ float softplusf(float x) {
  return (x > 20.f) ? x : __logf(1.f + __expf(x));
}

// async global->LDS, 16B per lane; LDS dest must be wave-uniform base,
// HW writes base + lane*16 (linear). Source addr is per-lane.
__device__ __forceinline__ void load_lds16(const void* g, void* l) {
  __builtin_amdgcn_global_load_lds(
      (const __attribute__((address_space(1))) unsigned int*)g,
      (__attribute__((address_space(3))) unsigned int*)l, 16, 0, 0);
}

// ---------- f32 -> bf16 convert (4 elems/thread) ----------
__global__ __launch_bounds__(256) void k_cvt(const float* __restrict__ s,
                                             __hip_bfloat16* __restrict__ d, int n) {
  int i = (blockIdx.x * 256 + threadIdx.x) * 4;
  if (i + 3 < n) {
    float4 v = *reinterpret_cast<const float4*>(s + i);
    d[i + 0] = __float2bfloat16(v.x);
    d[i + 1] = __float2bfloat16(v.y);
    d[i + 2] = __float2bfloat16(v.z);
    d[i + 3] = __float2bfloat16(v.w);
  }
}

// ---------- A = -exp(A_log) ----------
__global__ __launch_bounds__(256) void k_prepA(const float* __restrict__ alog,
                                               float* __restrict__ an, int n) {
  int i = blockIdx.x * 256 + threadIdx.x;
  if (i < n) an[i] = -__expf(alog[i]);
}

// ---------- bf16 NT GEMM via global_load_lds staging (m97 structure) ----------
// C[M,N] = A[M,K] * B[N,K]^T. 4 waves 2x2; OUTMODE: 0=f32, 1=bf16,
// 2=bf16 softplus(v + bias[col]).
template <int BM, int BN, int OUTMODE>
__global__ __launch_bounds__(256) void k_gemm_dl(const __hip_bfloat16* __restrict__ A, int lda,
                                                 const __hip_bfloat16* __restrict__ Bm, int ldb,
                                                 void* __restrict__ Cp, int ldc, int K,
                                                 const float* __restrict__ bias) {
  constexpr int BK = 32;
  constexpr int WM = BM / 2, WN = BN / 2;
  constexpr int FM = WM / 16, FN = WN / 16;

  const int tid = threadIdx.x;
  const int wid = tid >> 6, lane = tid & 63;
  const int wm = wid >> 1, wn = wid & 1;
  const int bm0 = blockIdx.y * BM, bn0 = blockIdx.x * BN;

  __shared__ short As[BM * BK];  // linear [BM][32], no pad (global_load_lds)
  __shared__ short Bs[BN * BK];

  f32x4 acc[FM][FN] = {};

  const int srow = wid * 16 + (lane >> 2);  // staging row within a 64-row group
  const int scol = (lane & 3) * 8;          // staging col (bf16 elems)
  const int lrow = lane & 15;
  const int lk = (lane >> 4) * 8;

  const __hip_bfloat16* Ag = &A[(size_t)(bm0 + srow) * lda + scol];
  const __hip_bfloat16* Bg = &Bm[(size_t)(bn0 + srow) * ldb + scol];

  for (int k0 = 0; k0 < K; k0 += BK) {
    __syncthreads();
#pragma unroll
    for (int i = 0; i < (BM + 63) / 64; i++)
      load_lds16(Ag + (size_t)i * 64 * lda + k0, &As[(i * 64 + wid * 16) * BK]);
#pragma unroll
    for (int i = 0; i < (BN + 63) / 64; i++)
      if ((BN % 64 == 0) || (i * 64 + wid * 16 < BN))
        load_lds16(Bg + (size_t)i * 64 * ldb + k0, &Bs[(i * 64 + wid * 16) * BK]);
    __syncthreads();

    short8 af[FM], bf[FN];
#pragma unroll
    for (int i = 0; i < FM; i++)
      af[i] = *reinterpret_cast<const short8*>(&As[(wm * WM + i * 16 + lrow) * BK + lk]);
#pragma unroll
    for (int j = 0; j < FN; j++)
      bf[j] = *reinterpret_cast<const short8*>(&Bs[(wn * WN + j * 16 + lrow) * BK + lk]);
#pragma unroll
    for (int i = 0; i < FM; i++)
#pragma unroll
      for (int j = 0; j < FN; j++)
        acc[i][j] = __builtin_amdgcn_mfma_f32_16x16x32_bf16(af[i], bf[j], acc[i][j], 0, 0, 0);
  }

  const int crow0 = bm0 + wm * WM + (lane >> 4) * 4;
  const int ccol0 = bn0 + wn * WN + lrow;
#pragma unroll
  for (int i = 0; i < FM; i++)
#pragma unroll
    for (int j = 0; j < FN; j++) {
      const int col = ccol0 + j * 16;
      float bv = 0.f;
      if constexpr (OUTMODE == 2) bv = bias[col];
#pragma unroll
      for (int r = 0; r < 4; r++) {
        const int row = crow0 + i * 16 + r;
        float v = acc[i][j][r];
        if constexpr (OUTMODE == 0)
          reinterpret_cast<float*>(Cp)[(size_t)row * ldc + col] = v;
        else if constexpr (OUTMODE == 1)
          reinterpret_cast<__hip_bfloat16*>(Cp)[(size_t)row * ldc + col] = __float2bfloat16(v);
        else
          reinterpret_cast<__hip_bfloat16*>(Cp)[(size_t)row * ldc + col] =
              __float2bfloat16(softplusf(v + bv));
      }
    }
}

// ---------- causal depthwise conv (width 4) + bias + silu ----------
__global__ __launch_bounds__(256) void k_conv(const __hip_bfloat16* __restrict__ xz,
                                              const float* __restrict__ cw,
                                              const float* __restrict__ cb,
                                              __hip_bfloat16* __restrict__ xc_bf16) {
  int idx = blockIdx.x * 256 + threadIdx.x;  // over M*DI
  int d = idx & (DI - 1);
  int ml = idx >> 11;
  int l = ml & (SEQLEN - 1);
  float acc = cb[d];
#pragma unroll
  for (int w = 0; w < DC; w++) {
    int li = l - 3 + w;
    if (li >= 0) {
      float xv = __bfloat162float(xz[(size_t)(ml - 3 + w) * NXZ + d]);
      acc += xv * cw[d * DC + w];
    }
  }
  float s = acc / (1.f + __expf(-acc));
  xc_bf16[idx] = __float2bfloat16(s);
}

// ---------- x_dbl[:, :64] -> bf16 dt_in ----------
__global__ __launch_bounds__(256) void k_dtin(const float* __restrict__ xdbl,
                                              __hip_bfloat16* __restrict__ dtin) {
  int i = blockIdx.x * 256 + threadIdx.x;  // M*64
  int r = i >> 6, c = i & 63;
  dtin[i] = __float2bfloat16(xdbl[(size_t)r * NXDBL + c]);
}

// ---------- scan pass 1: per-chunk local scan from h=0 -> (P, S) ----------
__global__ __launch_bounds__(256) void k_scan1(const __hip_bfloat16* __restrict__ delta_b,
                                               const float* __restrict__ xdbl,
                                               const __hip_bfloat16* __restrict__ xc,
                                               const float* __restrict__ Aneg,
                                               float* __restrict__ Pb,
                                               float* __restrict__ Sb) {
  const int tid = threadIdx.x;
  const int d = blockIdx.x * 256 + tid;
  const int c = blockIdx.y, b = blockIdx.z;
  const size_t row0 = (size_t)b * SEQLEN + (size_t)c * CL;

  __shared__ float Bs[CL][16];
  {
    int i = tid * 8;                 // 128*16 = 2048 floats, 8 per thread
    int li = i >> 4, n0 = i & 15;    // n0 in {0,8}
    const float* src = &xdbl[(row0 + li) * NXDBL + DTR + n0];
    *reinterpret_cast<float4*>(&Bs[li][n0]) = *reinterpret_cast<const float4*>(src);
    *reinterpret_cast<float4*>(&Bs[li][n0 + 4]) = *reinterpret_cast<const float4*>(src + 4);
  }

  float Ar[DS];
#pragma unroll
  for (int n = 0; n < DS; n++) Ar[n] = Aneg[d * DS + n];
  __syncthreads();

  float h[DS] = {};
  float sdelta = 0.f;
  size_t idx = row0 * DI + d;
  float nx_dt = __bfloat162float(delta_b[idx]);
  float nx_u = __bfloat162float(xc[idx]);
  for (int ls = 0; ls < CL; ls++) {
    float delta = nx_dt;
    float u = nx_u;
    if (ls + 1 < CL) {
      size_t idx2 = idx + DI;
      nx_dt = __bfloat162float(delta_b[idx2]);
      nx_u = __bfloat162float(xc[idx2]);
    }
    idx += DI;
    sdelta += delta;
    float du = delta * u;
#pragma unroll
    for (int n = 0; n < DS; n++) {
      float dA = __expf(delta * Ar[n]);
      h[n] = fmaf(h[n], dA, du * Bs[ls][n]);
    }
  }

  size_t base = (size_t)c * CS + ((size_t)b * DI + d) * DS;
#pragma unroll
  for (int n = 0; n < DS; n += 4) {
    float4 hv = {h[n], h[n + 1], h[n + 2], h[n + 3]};
    *reinterpret_cast<float4*>(&Sb[base + n]) = hv;
    float4 pv = {__expf(Ar[n] * sdelta), __expf(Ar[n + 1] * sdelta),
                 __expf(Ar[n + 2] * sdelta), __expf(Ar[n + 3] * sdelta)};
    *reinterpret_cast<float4*>(&Pb[base + n]) = pv;
  }
}

// ---------- scan pass 2: sequential scan over chunk transfer functions ----------
__global__ __launch_bounds__(256) void k_scan2(const float* __restrict__ Pb,
                                               const float* __restrict__ Sb,
                                               float* __restrict__ Hin) {
  size_t t = (size_t)blockIdx.x * 256 + threadIdx.x;  // < CS
  float h = 0.f;
  for (int c = 0; c < NCH; c++) {
    size_t o = (size_t)c * CS + t;
    Hin[o] = h;
    h = fmaf(Pb[o], h, Sb[o]);
  }
}

// ---------- scan pass 3: re-scan with correct h_init, compute y + gate ----------
__global__ __launch_bounds__(256) void k_scan3(const __hip_bfloat16* __restrict__ delta_b,
                                               const float* __restrict__ xdbl,
                                               const __hip_bfloat16* __restrict__ xc,
                                               const __hip_bfloat16* __restrict__ xz,
                                               const float* __restrict__ Aneg,
                                               const float* __restrict__ Dw,
                                               const float* __restrict__ Hin,
                                               __hip_bfloat16* __restrict__ yg) {
  const int tid = threadIdx.x;
  const int d = blockIdx.x * 256 + tid;
  const int c = blockIdx.y, b = blockIdx.z;
  const size_t row0 = (size_t)b * SEQLEN + (size_t)c * CL;

  __shared__ float BCs[CL][32];  // [l][0..15]=B, [16..31]=C
  {
    int i = tid * 16;              // 128*32 = 4096 floats, 16 per thread
    int li = i >> 5, n0 = i & 31;  // n0 in {0,16}
    const float* src = &xdbl[(row0 + li) * NXDBL + DTR + n0];
#pragma unroll
    for (int q = 0; q < 4; q++)
      *reinterpret_cast<float4*>(&BCs[li][n0 + q * 4]) =
          *reinterpret_cast<const float4*>(src + q * 4);
  }

  float Ar[DS];
#pragma unroll
  for (int n = 0; n < DS; n++) Ar[n] = Aneg[d * DS + n];
  const float Dv = Dw[d];

  float h[DS];
  {
    size_t hbase = (size_t)c * CS + ((size_t)b * DI + d) * DS;
#pragma unroll
    for (int n = 0; n < DS; n += 4) {
      float4 hv = *reinterpret_cast<const float4*>(&Hin[hbase + n]);
      h[n] = hv.x; h[n + 1] = hv.y; h[n + 2] = hv.z; h[n + 3] = hv.w;
    }
  }
  __syncthreads();

  size_t idx = row0 * DI + d;
  float nx_dt = __bfloat162float(delta_b[idx]);
  float nx_u = __bfloat162float(xc[idx]);
  float nx_z = __bfloat162float(xz[row0 * NXZ + DI + d]);
  for (int ls = 0; ls < CL; ls++) {
    const size_t cur = idx;
    float delta = nx_dt;
    float u = nx_u;
    float zv = nx_z;
    if (ls + 1 < CL) {
      size_t idx2 = idx + DI;
      nx_dt = __bfloat162float(delta_b[idx2]);
      nx_u = __bfloat162float(xc[idx2]);
      nx_z = __bfloat162float(xz[(row0 + ls + 1) * NXZ + DI + d]);
    }
    idx += DI;
    float du = delta * u;
    float y = 0.f;
#pragma unroll
    for (int n = 0; n < DS; n++) {
      float dA = __expf(delta * Ar[n]);
      h[n] = fmaf(h[n], dA, du * BCs[ls][n]);
      y = fmaf(h[n], BCs[ls][16 + n], y);
    }
    float sz = zv / (1.f + __expf(-zv));
    float out = (y + u * Dv) * sz;
    yg[cur] = __float2bfloat16(out);
  }
}

extern "C" void kernel_launch(void* const* d_in, const int* in_sizes, int n_in,
                              void* d_out, int out_size, void* d_ws, size_t ws_size,
                              hipStream_t stream) {
  const float* hs = (const float*)d_in[0];
  const float* w_in = (const float*)d_in[1];
  const float* conv_w = (const float*)d_in[2];
  const float* conv_b = (const float*)d_in[3];
  const float* w_xp = (const float*)d_in[4];
  const float* w_dt = (const float*)d_in[5];
  const float* dt_b = (const float*)d_in[6];
  const float* A_log = (const float*)d_in[7];
  const float* Dw = (const float*)d_in[8];
  const float* w_out = (const float*)d_in[9];
  float* out = (float*)d_out;

  char* ws = (char*)d_ws;
  size_t off = 0;
  auto alloc = [&](size_t bytes) {
    void* p = ws + off;
    off += (bytes + 255) & ~(size_t)255;
    return p;
  };

  __hip_bfloat16* hs_b   = (__hip_bfloat16*)alloc((size_t)M * DM * 2);     // [0, 16Mi)
  __hip_bfloat16* win_b  = (__hip_bfloat16*)alloc((size_t)NXZ * DM * 2);   // [16Mi, 24Mi)
  __hip_bfloat16* wxp_b  = (__hip_bfloat16*)alloc((size_t)NXDBL * DI * 2);
  __hip_bfloat16* wdt_b  = (__hip_bfloat16*)alloc((size_t)DI * DTR * 2);
  __hip_bfloat16* wout_b = (__hip_bfloat16*)alloc((size_t)DM * DI * 2);
  float*          Aneg   = (float*)alloc((size_t)DI * DS * 4);
  __hip_bfloat16* xz_b   = (__hip_bfloat16*)alloc((size_t)M * NXZ * 2);
  __hip_bfloat16* xc_b   = (__hip_bfloat16*)alloc((size_t)M * DI * 2);
  float*          xdbl   = (float*)alloc((size_t)M * NXDBL * 4);
  __hip_bfloat16* dtin_b = (__hip_bfloat16*)alloc((size_t)M * DTR * 2);
  __hip_bfloat16* delta_b= (__hip_bfloat16*)alloc((size_t)M * DI * 2);
  __hip_bfloat16* yg_b   = (__hip_bfloat16*)alloc((size_t)M * DI * 2);

  // Scan chunk-state buffers alias hs_b/win_b (dead after GEMM1; each pass
  // fully rewrites them, so graph replay is deterministic).
  float* Pb  = (float*)(ws + 0);
  float* Sb  = (float*)(ws + ((size_t)8 << 20));
  float* Hin = (float*)(ws + ((size_t)16 << 20));

  // 1) conversions
  k_cvt<<<(M * DM) / 1024, 256, 0, stream>>>(hs, hs_b, M * DM);
  k_cvt<<<(NXZ * DM) / 1024, 256, 0, stream>>>(w_in, win_b, NXZ * DM);
  k_cvt<<<(NXDBL * DI) / 1024, 256, 0, stream>>>(w_xp, wxp_b, NXDBL * DI);
  k_cvt<<<(DI * DTR) / 1024, 256, 0, stream>>>(w_dt, wdt_b, DI * DTR);
  k_cvt<<<(DM * DI) / 1024, 256, 0, stream>>>(w_out, wout_b, DM * DI);
  k_prepA<<<(DI * DS) / 256, 256, 0, stream>>>(A_log, Aneg, DI * DS);

  // 2) xz = hs @ in_proj_w^T  (M x 4096, bf16 out)
  k_gemm_dl<128, 128, 1><<<dim3(NXZ / 128, M / 128), 256, 0, stream>>>(
      hs_b, DM, win_b, DM, xz_b, NXZ, DM, nullptr);

  // 3) conv + silu -> x_conv (bf16)
  k_conv<<<(M * DI) / 256, 256, 0, stream>>>(xz_b, conv_w, conv_b, xc_b);

  // 4) x_dbl = x_conv @ x_proj_w^T  (M x 96, fp32)
  k_gemm_dl<64, 96, 0><<<dim3(1, M / 64), 256, 0, stream>>>(
      xc_b, DI, wxp_b, DI, xdbl, NXDBL, DI, nullptr);

  // 5) dt_in -> bf16
  k_dtin<<<(M * DTR) / 256, 256, 0, stream>>>(xdbl, dtin_b);

  // 6) delta = softplus(dt_in @ dt_proj_w^T + dt_b)  (M x 2048, bf16, fused)
  k_gemm_dl<128, 128, 2><<<dim3(DI / 128, M / 128), 256, 0, stream>>>(
      dtin_b, DTR, wdt_b, DTR, delta_b, DI, DTR, dt_b);

  // 7) chunked parallel scan
  k_scan1<<<dim3(DI / 256, NCH, BATCH), 256, 0, stream>>>(delta_b, xdbl, xc_b,
                                                          Aneg, Pb, Sb);
  k_scan2<<<(int)(CS / 256), 256, 0, stream>>>(Pb, Sb, Hin);
  k_scan3<<<dim3(DI / 256, NCH, BATCH), 256, 0, stream>>>(delta_b, xdbl, xc_b,
                                                          xz_b, Aneg, Dw, Hin, yg_b);

  // 8) out = y_gated @ out_proj_w^T  (M x 1024, fp32)
  k_gemm_dl<128, 128, 0><<<dim3(DM / 128, M / 128), 256, 0, stream>>>(
      yg_b, DI, wout_b, DI, out, DM, DI, nullptr);
}